// Round 7
// baseline (331.184 us; speedup 1.0000x reference)
//
#include <hip/hip_runtime.h>
#include <hip/hip_bf16.h>

typedef __attribute__((ext_vector_type(8))) short short8;
typedef __attribute__((ext_vector_type(4))) float f32x4;

#define T_PRE 64
#define T_FWD 80
#define BATCHN 4096

#define HP 264   // h row pitch (bf16 elems): 256 + 8 pad
#define IP 136   // input row pitch: 128 + 8 pad

// ---- ws layout (ushort offsets) ----
// wrnn [256][384] bf16 : rows j = [W_hh[j] | W_ih[j]]
// wrec [256][384] bf16 : rows j = [A^2[j] | (A*B)[j] | B[j]]     (2-step SS)
// ywt  [2][64][384] bf16: i=0 rows o=[CA | CB | 0], i=1 [CA^2 | CAB | CB]
// f32: brnn[256]=b_ih+b_hh, brec[256]=(A+I)(A_b+B_b), yb[2][64]
// f32 scratch: CA[64][256] (prep_a -> prep_b)
#define U_WRNN 0
#define U_WREC 98304
#define U_YW   196608
#define U_FB   245760
#define U_CAF  247040

// prep_a work-unit ranges (1 unit = 1 thread)
#define A_S0 24576   // wrnn float4 copy
#define A_S1 32768   // + 8192 : A^2 -> wrec[,0:256)
#define A_S2 34816   // + 2048 : AB  -> wrec[,256:320)
#define A_S3 38912   // + 4096 : B copy -> wrec[,320:384)
#define A_S4 40960   // + 2048 : CA -> caf (f32) + ywt0[,0:256)
#define A_S5 41472   // +  512 : CB -> ywt0[,256:320) + ywt1[,320:384)
#define A_S6 42496   // + 1024 : zeros -> ywt0[,320:384)
#define A_S7 42560   // +   64 : brnn
#define A_S8 42816   // +  256 : brec
// prep_b ranges
#define B_T0 2048    // CA^2 -> ywt1[,0:256)
#define B_T1 2560    // + 512 : CAB -> ywt1[,256:320)
#define B_T2 2688    // + 128 : yb

__device__ __forceinline__ unsigned short bf1(float a) {
  unsigned ua = __float_as_uint(a);
  return (unsigned short)((ua + 0x7fffu + ((ua >> 16) & 1u)) >> 16);
}
__device__ __forceinline__ unsigned pk(float a, float b) {
  __hip_bfloat162 h = __float22bfloat162_rn(make_float2(a, b));
  unsigned u;
  __builtin_memcpy(&u, &h, 4);
  return u;
}
__device__ __forceinline__ float tanh_fast(float x) {
  float e = __expf(2.0f * x);  // saturates correctly for large |x|
  return 1.0f - 2.0f * __builtin_amdgcn_rcpf(e + 1.0f);
}

// One row x 8 cols of OUT = LHS[M][256] * RHS[256][N].
// Each of the 8 outputs is a SINGLE ascending-k FMA chain -> numerically
// identical to the scalar prep (absmax preserved). 3 float4 loads per
// 32 FMAs (vs 64 scalar loads) kills the load-issue bottleneck.
__device__ __forceinline__ void gemm_row8(const float* __restrict__ L, int j,
                                          const float* __restrict__ R, int N,
                                          int c0, float* __restrict__ o8) {
  f32x4 a0 = {0.f, 0.f, 0.f, 0.f}, a1 = {0.f, 0.f, 0.f, 0.f};
  for (int kk4 = 0; kk4 < 64; ++kk4) {
    f32x4 lv = *(const f32x4*)(L + j * 256 + kk4 * 4);
#pragma unroll
    for (int i = 0; i < 4; ++i) {
      const float* rp = R + (size_t)(kk4 * 4 + i) * N + c0;
      f32x4 r0 = *(const f32x4*)rp;
      f32x4 r1 = *(const f32x4*)(rp + 4);
      a0 += lv[i] * r0;
      a1 += lv[i] * r1;
    }
  }
#pragma unroll
  for (int i = 0; i < 4; ++i) { o8[i] = a0[i]; o8[4 + i] = a1[i]; }
}

__device__ __forceinline__ void store_bf8(unsigned short* __restrict__ dst,
                                          const float* __restrict__ o8) {
  unsigned r0 = pk(o8[0], o8[1]), r1 = pk(o8[2], o8[3]);
  unsigned r2 = pk(o8[4], o8[5]), r3 = pk(o8[6], o8[7]);
  *(uint4*)dst = make_uint4(r0, r1, r2, r3);
}

// prep_a: wrnn copy, wrec (A^2|AB|B), CA (f32+bf16), CB, ywt0 zeros, biases
__global__ void prep_a_kernel(const float* __restrict__ A_w, const float* __restrict__ A_b,
                              const float* __restrict__ B_w, const float* __restrict__ B_b,
                              const float* __restrict__ W_ih, const float* __restrict__ b_ih,
                              const float* __restrict__ W_hh, const float* __restrict__ b_hh,
                              const float* __restrict__ C_w,
                              unsigned short* __restrict__ ws) {
  int u = blockIdx.x * 256 + threadIdx.x;
  float* fb = (float*)(ws + U_FB);
  float* caf = (float*)(ws + U_CAF);
  if (u < A_S0) {                      // wrnn: float4 copy -> bf16x4
    int j = u / 96, k = (u - j * 96) * 4;
    f32x4 v = (k < 256) ? *(const f32x4*)(W_hh + j * 256 + k)
                        : *(const f32x4*)(W_ih + j * 128 + (k - 256));
    *(uint2*)(ws + U_WRNN + j * 384 + k) = make_uint2(pk(v[0], v[1]), pk(v[2], v[3]));
  } else if (u < A_S1) {               // A^2
    int u1 = u - A_S0;
    int j = u1 >> 5, c0 = (u1 & 31) * 8;
    float o8[8];
    gemm_row8(A_w, j, A_w, 256, c0, o8);
    store_bf8(ws + U_WREC + j * 384 + c0, o8);
  } else if (u < A_S2) {               // AB
    int u2 = u - A_S1;
    int j = u2 >> 3, c0 = (u2 & 7) * 8;
    float o8[8];
    gemm_row8(A_w, j, B_w, 64, c0, o8);
    store_bf8(ws + U_WREC + j * 384 + 256 + c0, o8);
  } else if (u < A_S3) {               // B copy
    int u3 = u - A_S2;
    int j = u3 >> 4, c = (u3 & 15) * 4;
    f32x4 v = *(const f32x4*)(B_w + j * 64 + c);
    *(uint2*)(ws + U_WREC + j * 384 + 320 + c) = make_uint2(pk(v[0], v[1]), pk(v[2], v[3]));
  } else if (u < A_S4) {               // CA -> caf f32 + ywt0 bf16
    int u4 = u - A_S3;
    int o = u4 >> 5, c0 = (u4 & 31) * 8;
    float o8[8];
    gemm_row8(C_w, o, A_w, 256, c0, o8);
    *(f32x4*)(caf + o * 256 + c0) = *(f32x4*)o8;
    *(f32x4*)(caf + o * 256 + c0 + 4) = *(f32x4*)(o8 + 4);
    store_bf8(ws + U_YW + o * 384 + c0, o8);
  } else if (u < A_S5) {               // CB -> ywt0[,256:320) + ywt1[,320:384)
    int u5 = u - A_S4;
    int o = u5 >> 3, c0 = (u5 & 7) * 8;
    float o8[8];
    gemm_row8(C_w, o, B_w, 64, c0, o8);
    store_bf8(ws + U_YW + o * 384 + 256 + c0, o8);
    store_bf8(ws + U_YW + 24576 + o * 384 + 320 + c0, o8);
  } else if (u < A_S6) {               // ywt0[,320:384) zeros
    int u6 = u - A_S5;
    int o = u6 >> 4, c = (u6 & 15) * 4;
    *(uint2*)(ws + U_YW + o * 384 + 320 + c) = make_uint2(0u, 0u);
  } else if (u < A_S7) {               // brnn float4
    int u7 = u - A_S6;
    f32x4 a = *(const f32x4*)(b_ih + u7 * 4);
    f32x4 b = *(const f32x4*)(b_hh + u7 * 4);
    *(f32x4*)(fb + u7 * 4) = a + b;
  } else if (u < A_S8) {               // brec row j (single chain per lane-of-4)
    int j = u - A_S7;
    f32x4 s = {0.f, 0.f, 0.f, 0.f};
    for (int kk4 = 0; kk4 < 64; ++kk4) {
      f32x4 la = *(const f32x4*)(A_w + j * 256 + kk4 * 4);
      f32x4 ab = *(const f32x4*)(A_b + kk4 * 4);
      f32x4 bb = *(const f32x4*)(B_b + kk4 * 4);
      s += la * (ab + bb);
    }
    fb[256 + j] = ((s[0] + s[1]) + (s[2] + s[3])) + A_b[j] + B_b[j];
  }
}

// prep_b: CA^2, CAB (need caf), yb
__global__ void prep_b_kernel(const float* __restrict__ A_w, const float* __restrict__ A_b,
                              const float* __restrict__ B_w, const float* __restrict__ B_b,
                              const float* __restrict__ C_w, const float* __restrict__ C_b,
                              unsigned short* __restrict__ ws) {
  int u = blockIdx.x * 256 + threadIdx.x;
  float* fb = (float*)(ws + U_FB);
  const float* caf = (const float*)(ws + U_CAF);
  if (u < B_T0) {                      // CA^2 = caf * A
    int o = u >> 5, c0 = (u & 31) * 8;
    float o8[8];
    gemm_row8(caf, o, A_w, 256, c0, o8);
    store_bf8(ws + U_YW + 24576 + o * 384 + c0, o8);
  } else if (u < B_T1) {               // CAB = caf * B
    int u1 = u - B_T0;
    int o = u1 >> 3, c0 = (u1 & 7) * 8;
    float o8[8];
    gemm_row8(caf, o, B_w, 64, c0, o8);
    store_bf8(ws + U_YW + 24576 + o * 384 + 256 + c0, o8);
  } else if (u < B_T2) {               // yb[2][64]
    int u2 = u - B_T1;
    int which = u2 >> 6, o = u2 & 63;
    f32x4 s = {0.f, 0.f, 0.f, 0.f};
    for (int kk4 = 0; kk4 < 64; ++kk4) {
      f32x4 lc = *(const f32x4*)(C_w + o * 256 + kk4 * 4);
      if (which) lc += *(const f32x4*)(caf + o * 256 + kk4 * 4);
      f32x4 ab = *(const f32x4*)(A_b + kk4 * 4);
      f32x4 bb = *(const f32x4*)(B_b + kk4 * 4);
      s += lc * (ab + bb);
    }
    fb[512 + which * 64 + o] = ((s[0] + s[1]) + (s[2] + s[3])) + C_b[o];
  }
}

// Persistent: 256 blocks x 16 batch rows, 512 threads (8 waves, 2/SIMD).
// R5 structure exactly (unroll-2 pragmas reverted: R6 showed +5us regression).
__global__ __launch_bounds__(512) __attribute__((amdgpu_waves_per_eu(2, 2)))
void rnn_ss_kernel(
    const float* __restrict__ pre_x, const float* __restrict__ pre_y,
    const float* __restrict__ fwd_x,
    const unsigned short* __restrict__ ws, float* __restrict__ out) {
  __shared__ unsigned short hbuf[2][16 * HP];
  __shared__ unsigned short ibuf[2][16 * IP];

  const int tid = threadIdx.x;
  const int lane = tid & 63;
  const int w = tid >> 6;      // wave 0..7
  const int col = lane & 15;   // batch col (B/D) / A row-in-tile
  const int q = lane >> 4;     // quad
  const int r0 = blockIdx.x * 16;
  const int srow = (tid & 255) >> 4;  // staging batch row 0..15
  const int sc4 = tid & 15;           // staging float4 col 0..15
  const bool xhalf = (tid >= 256);    // waves 4-7 stage x (and x1); 0-3 stage y (and x2)

  // zero hbuf[0] h region -> h0 = 0
#pragma unroll
  for (int it = 0; it < 2; ++it) {
    int i = tid + it * 512;
    int r = i >> 6, c = (i & 63) * 4;
    *(uint2*)&hbuf[0][r * HP + c] = make_uint2(0u, 0u);
  }

  const float* fbias = (const float*)(ws + U_FB);
  int cur = 0;

  // ---------------- encoder tanh-RNN (K = 384) ----------------
  {
    short8 wf[2][12];
#pragma unroll
    for (int mt = 0; mt < 2; ++mt)
#pragma unroll
      for (int kf = 0; kf < 12; ++kf)
        wf[mt][kf] = *(const short8*)(ws + U_WRNN +
                       (size_t)(w * 32 + mt * 16 + col) * 384 + kf * 32 + q * 8);
    f32x4 br[2];
#pragma unroll
    for (int mt = 0; mt < 2; ++mt)
      br[mt] = *(const f32x4*)(fbias + w * 32 + mt * 16 + q * 4);

    // stage xy_0 into ibuf[0]
    {
      f32x4 v = xhalf ? *(const f32x4*)(pre_x + (size_t)(r0 + srow) * 64 + sc4 * 4)
                      : *(const f32x4*)(pre_y + (size_t)(r0 + srow) * 64 + sc4 * 4);
      *(uint2*)&ibuf[0][srow * IP + (xhalf ? 0 : 64) + sc4 * 4] =
          make_uint2(pk(v[0], v[1]), pk(v[2], v[3]));
    }

    for (int t = 0; t < T_PRE; ++t) {
      f32x4 nv;
      if (t < T_PRE - 1) {
        nv = xhalf ? *(const f32x4*)(pre_x + ((size_t)(t + 1) * BATCHN + r0 + srow) * 64 + sc4 * 4)
                   : *(const f32x4*)(pre_y + ((size_t)(t + 1) * BATCHN + r0 + srow) * 64 + sc4 * 4);
      } else {
        // hand off to SS: stage fwd_x[0] at [0,64) and fwd_x[1] at [64,128)
        nv = xhalf ? *(const f32x4*)(fwd_x + (size_t)(r0 + srow) * 64 + sc4 * 4)
                   : *(const f32x4*)(fwd_x + ((size_t)BATCHN + r0 + srow) * 64 + sc4 * 4);
      }
      __syncthreads();  // h_t (hbuf[cur]) and xy_t (ibuf[cur]) visible
      const unsigned short* hc = hbuf[cur];
      const unsigned short* ic = ibuf[cur];
      short8 bfr[12];
#pragma unroll
      for (int kf = 0; kf < 8; ++kf)
        bfr[kf] = *(const short8*)&hc[col * HP + kf * 32 + q * 8];
#pragma unroll
      for (int kf = 8; kf < 12; ++kf)
        bfr[kf] = *(const short8*)&ic[col * IP + (kf - 8) * 32 + q * 8];
      f32x4 acc[2];
#pragma unroll
      for (int mt = 0; mt < 2; ++mt) acc[mt] = br[mt];
#pragma unroll
      for (int kf = 0; kf < 12; ++kf)
#pragma unroll
        for (int mt = 0; mt < 2; ++mt)
          acc[mt] = __builtin_amdgcn_mfma_f32_16x16x32_bf16(wf[mt][kf], bfr[kf], acc[mt], 0, 0, 0);
      unsigned short* hn_ = hbuf[cur ^ 1];
#pragma unroll
      for (int mt = 0; mt < 2; ++mt) {
        float t0 = tanh_fast(acc[mt][0]), t1 = tanh_fast(acc[mt][1]);
        float t2 = tanh_fast(acc[mt][2]), t3 = tanh_fast(acc[mt][3]);
        *(uint2*)&hn_[col * HP + w * 32 + mt * 16 + q * 4] =
            make_uint2(pk(t0, t1), pk(t2, t3));
      }
      *(uint2*)&ibuf[cur ^ 1][srow * IP + (xhalf ? 0 : 64) + sc4 * 4] =
          make_uint2(pk(nv[0], nv[1]), pk(nv[2], nv[3]));
      cur ^= 1;
    }
  }

  // -------- state-space rollout, 2-step unrolled (K = 384) + fused y --------
  {
    short8 rf[2][12];
#pragma unroll
    for (int mt = 0; mt < 2; ++mt)
#pragma unroll
      for (int kf = 0; kf < 12; ++kf)
        rf[mt][kf] = *(const short8*)(ws + U_WREC +
                       (size_t)(w * 32 + mt * 16 + col) * 384 + kf * 32 + q * 8);
    f32x4 brv[2];
#pragma unroll
    for (int mt = 0; mt < 2; ++mt)
      brv[mt] = *(const f32x4*)(fbias + 256 + w * 32 + mt * 16 + q * 4);

    const int yi = w >> 2;   // 0 -> y_{2b+1}, 1 -> y_{2b+2}
    const int yc = w & 3;    // out-dim 16-block
    short8 yf[12];
#pragma unroll
    for (int kf = 0; kf < 12; ++kf)
      yf[kf] = *(const short8*)(ws + U_YW +
                 (size_t)(yi * 64 + yc * 16 + col) * 384 + kf * 32 + q * 8);
    f32x4 ybv = *(const f32x4*)(fbias + 512 + yi * 64 + yc * 16 + q * 4);

    f32x4 ysav;
    for (int b = 0; b < T_FWD / 2; ++b) {
      f32x4 nv;
      const bool st = (b < T_FWD / 2 - 1);
      if (st)
        nv = *(const f32x4*)(fwd_x +
              ((size_t)(2 * b + 2 + (xhalf ? 0 : 1)) * BATCHN + r0 + srow) * 64 + sc4 * 4);
      __syncthreads();  // h_{2b} (hbuf[cur]) and x_{2b+1},x_{2b+2} (ibuf[cur]) visible
      // deferred y-store for block b-1: a full block of compute covers store-ack
      if (b > 0)
        *(f32x4*)(out + ((size_t)(2 * b - 2 + yi) * BATCHN + r0 + col) * 64 + yc * 16 + q * 4) = ysav;
      const unsigned short* hc = hbuf[cur];
      const unsigned short* ic = ibuf[cur];
      short8 bfr[12];
#pragma unroll
      for (int kf = 0; kf < 8; ++kf)
        bfr[kf] = *(const short8*)&hc[col * HP + kf * 32 + q * 8];
#pragma unroll
      for (int kf = 8; kf < 12; ++kf)
        bfr[kf] = *(const short8*)&ic[col * IP + (kf - 8) * 32 + q * 8];
      f32x4 acc[2];
#pragma unroll
      for (int mt = 0; mt < 2; ++mt) acc[mt] = brv[mt];
      f32x4 yacc = ybv;
#pragma unroll
      for (int kf = 0; kf < 12; ++kf) {
        acc[0] = __builtin_amdgcn_mfma_f32_16x16x32_bf16(rf[0][kf], bfr[kf], acc[0], 0, 0, 0);
        acc[1] = __builtin_amdgcn_mfma_f32_16x16x32_bf16(rf[1][kf], bfr[kf], acc[1], 0, 0, 0);
        yacc   = __builtin_amdgcn_mfma_f32_16x16x32_bf16(yf[kf],    bfr[kf], yacc,   0, 0, 0);
      }
      ysav = yacc;
      unsigned short* hn_ = hbuf[cur ^ 1];
#pragma unroll
      for (int mt = 0; mt < 2; ++mt)
        *(uint2*)&hn_[col * HP + w * 32 + mt * 16 + q * 4] =
            make_uint2(pk(acc[mt][0], acc[mt][1]), pk(acc[mt][2], acc[mt][3]));
      if (st)
        *(uint2*)&ibuf[cur ^ 1][srow * IP + (xhalf ? 0 : 64) + sc4 * 4] =
            make_uint2(pk(nv[0], nv[1]), pk(nv[2], nv[3]));
      cur ^= 1;
    }
    // final y (block 39): rows 78+yi
    *(f32x4*)(out + ((size_t)(78 + yi) * BATCHN + r0 + col) * 64 + yc * 16 + q * 4) = ysav;
  }
}

extern "C" void kernel_launch(void* const* d_in, const int* in_sizes, int n_in,
                              void* d_out, int out_size, void* d_ws, size_t ws_size,
                              hipStream_t stream) {
  const float* pre_x = (const float*)d_in[0];
  const float* pre_y = (const float*)d_in[1];
  const float* fwd_x = (const float*)d_in[2];
  const float* A_w   = (const float*)d_in[3];
  const float* A_b   = (const float*)d_in[4];
  const float* B_w   = (const float*)d_in[5];
  const float* B_b   = (const float*)d_in[6];
  const float* C_w   = (const float*)d_in[7];
  const float* C_b   = (const float*)d_in[8];
  const float* W_ih  = (const float*)d_in[9];
  const float* b_ih  = (const float*)d_in[10];
  const float* W_hh  = (const float*)d_in[11];
  const float* b_hh  = (const float*)d_in[12];
  unsigned short* ws = (unsigned short*)d_ws;
  float* out = (float*)d_out;

  prep_a_kernel<<<(A_S8 + 255) / 256, 256, 0, stream>>>(
      A_w, A_b, B_w, B_b, W_ih, b_ih, W_hh, b_hh, C_w, ws);
  prep_b_kernel<<<(B_T2 + 255) / 256, 256, 0, stream>>>(
      A_w, A_b, B_w, B_b, C_w, C_b, ws);
  rnn_ss_kernel<<<BATCHN / 16, 512, 0, stream>>>(pre_x, pre_y, fwd_x, ws, out);
}